// Round 5
// baseline (569.255 us; speedup 1.0000x reference)
//
#include <hip/hip_runtime.h>
#include <hip/hip_bf16.h>
#include <math.h>

#define D_MODEL 2048
#define N_HEADS 16
#define D_HEAD  128
#define BATCH   64
#define SEQ     128
#define BT      (BATCH*SEQ)   // 8192 rows
#define LDF     6144          // fused QKV row stride
#define KOFF    2048
#define VOFF    4096

typedef __bf16 bf16;
typedef __attribute__((ext_vector_type(8))) __bf16 bf16x8;
typedef __attribute__((ext_vector_type(4))) float  f32x4;

__device__ __forceinline__ f32x4 mfma16(bf16x8 a, bf16x8 b, f32x4 c) {
    return __builtin_amdgcn_mfma_f32_16x16x32_bf16(a, b, c, 0, 0, 0);
}

__device__ __forceinline__ bf16x8 cvt8_f32(const float* p) {
    f32x4 lo = *(const f32x4*)p;
    f32x4 hi = *(const f32x4*)(p + 4);
    bf16x8 r;
    r[0] = (bf16)lo[0]; r[1] = (bf16)lo[1]; r[2] = (bf16)lo[2]; r[3] = (bf16)lo[3];
    r[4] = (bf16)hi[0]; r[5] = (bf16)hi[1]; r[6] = (bf16)hi[2]; r[7] = (bf16)hi[3];
    return r;
}

// async global->LDS, 16 B/lane; LDS dest = wave-uniform base + lane*16 (m104)
__device__ __forceinline__ void gl2lds16(const bf16* g, bf16* l) {
    __builtin_amdgcn_global_load_lds(
        (const __attribute__((address_space(1))) void*)g,
        (__attribute__((address_space(3))) void*)l, 16, 0, 0);
}

// rope 8 consecutive d-elements (4 even/odd pairs)
__device__ __forceinline__ bf16x8 rope8(bf16x8 v, int tpos, int pair0) {
    bf16x8 r;
    for (int m = 0; m < 4; ++m) {
        int i = pair0 + m;
        float theta = __expf((float)(2 * i) * (-9.210340371976184f / 128.0f));
        float ang   = (float)tpos * theta;
        float sn, cs;
        __sincosf(ang, &sn, &cs);
        float e = (float)v[2 * m], o = (float)v[2 * m + 1];
        r[2 * m]     = (bf16)(e * cs - o * sn);
        r[2 * m + 1] = (bf16)(e * sn + o * cs);
    }
    return r;
}

// ---------------------------------------------------------------------------
__global__ __launch_bounds__(256) void cvt_kernel(const float* __restrict__ src,
                                                  bf16* __restrict__ dst, int n8)
{
    int i = blockIdx.x * 256 + threadIdx.x;
    if (i < n8) *(bf16x8*)(dst + (size_t)i * 8) = cvt8_f32(src + (size_t)i * 8);
}

__global__ __launch_bounds__(256) void cvt_w3(const float* __restrict__ w0,
                                              const float* __restrict__ w1,
                                              const float* __restrict__ w2,
                                              bf16* __restrict__ dst)
{
    int i   = blockIdx.x * 256 + threadIdx.x;     // < 3*2^19
    int sel = i >> 19;
    int off = i & ((1 << 19) - 1);
    const float* s = (sel == 0) ? w0 : (sel == 1) ? w1 : w2;
    *(bf16x8*)(dst + (size_t)i * 8) = cvt8_f32(s + (size_t)off * 8);
}

// ---------------------------------------------------------------------------
// gemm256: C[M,N] = A[M,K] @ B[N,K]^T, bf16 in, OutT out.
// 256x256 tile, BK=64, 512 thr = 8 waves (2Mx4N), per-wave 128x64 output.
//
// k-slot SOFTWARE PIPELINE (2 phases per K-tile, frag regs double-banked):
//   even phase p=2t: [STAGE8 tile t+1 -> other buf] [12 ds_read k1 -> bank1]
//                    bar; lgkmcnt(12) (drains k0 reads issued LAST phase,
//                    already LDS-serviced during last MFMA window);
//                    32 MFMA on bank0; vmcnt(0) (drains the 8 stages issued
//                    at phase start, ~full MFMA window of cover); bar
//   odd  phase:      [12 ds_read k0(t+1) from other buf -> bank0]
//                    bar; lgkmcnt(12); 32 MFMA on bank1; bar
// LDS service of next phase's reads overlaps this phase's MFMA; the counted
// lgkmcnt finds them complete. All buffer hazards are ordered by
// counter-drain-then-barrier (no timing races):
//   RAW stage->read: stages drained by vmcnt at even-phase end + bar, reads
//     issue in the following odd phase.
//   WAR read->stage: buf X's last reads (k1) drained by odd-phase lgkm + bar
//     one tile earlier than X is re-staged.
// Frag regs: 2 banks x (8 A + 4 B) bf16x8 = 96 VGPR; acc 8x4 f32x4 in AGPR.
// ---------------------------------------------------------------------------

#define BAR() __builtin_amdgcn_s_barrier()
#define SB0() __builtin_amdgcn_sched_barrier(0)

// 12 ds_reads of k-slot KS of buffer BSEL into frag bank BK
#define READS(BSEL, KS, BK) do {                                              \
    _Pragma("unroll") for (int ii = 0; ii < 8; ++ii)                          \
        Fa[BK][ii] = *(const bf16x8*)&As[BSEL][aoff[ii] + ksw[KS]];           \
    _Pragma("unroll") for (int jj = 0; jj < 4; ++jj)                          \
        Fb[BK][jj] = *(const bf16x8*)&Bs[BSEL][bof[jj] + ksw[KS]];            \
    } while (0)

// 32 MFMA consuming frag bank BK
#define MQ32(BK) do {                                                         \
    __builtin_amdgcn_s_setprio(1);                                            \
    _Pragma("unroll") for (int ii = 0; ii < 8; ++ii)                          \
    _Pragma("unroll") for (int jj = 0; jj < 4; ++jj)                          \
        acc[ii][jj] = mfma16(Fa[BK][ii], Fb[BK][jj], acc[ii][jj]);            \
    __builtin_amdgcn_s_setprio(0);                                            \
    } while (0)

// stage full K-tile tt (A 4 chunks + B 4 chunks, 8KB each) into buffer BSEL
#define STAGE8(BSEL, tt) do {                                                 \
    const size_t _k = (size_t)(tt) * 64;                                      \
    _Pragma("unroll") for (int c = 0; c < 4; ++c) {                           \
        gl2lds16(Ag + (size_t)c * 64 * lda + _k, &As[BSEL][c*4096 + w*512]);  \
        gl2lds16(Bg + (size_t)c * 64 * ldb + _k, &Bs[BSEL][c*4096 + w*512]);  \
    } } while (0)

// MODE: 0 = steady; 1 = last tile (no stage, no next-tile reads)
#define TILE(BSEL, OSEL, tt, MODE) do {                                       \
    /* ---- even phase: MFMA k0(bank0); prefetch k1->bank1; stage t+1 ---- */ \
    if (MODE == 0) STAGE8(OSEL, (tt) + 1);                                    \
    READS(BSEL, 1, 1);                                                        \
    SB0(); BAR();                                                             \
    asm volatile("s_waitcnt lgkmcnt(12)" ::: "memory"); SB0();                \
    MQ32(0);                                                                  \
    if (MODE == 0) asm volatile("s_waitcnt vmcnt(0)" ::: "memory");           \
    SB0(); BAR();                                                             \
    /* ---- odd phase: MFMA k1(bank1); prefetch k0(t+1)->bank0 ---- */        \
    if (MODE == 0) READS(OSEL, 0, 0);                                         \
    SB0(); BAR();                                                             \
    if (MODE == 0) { asm volatile("s_waitcnt lgkmcnt(12)" ::: "memory"); }    \
    else           { asm volatile("s_waitcnt lgkmcnt(0)"  ::: "memory"); }    \
    SB0();                                                                    \
    MQ32(1);                                                                  \
    SB0(); BAR();                                                             \
    } while (0)

template<typename OutT>
__global__ __launch_bounds__(512, 2) void gemm256(const bf16* __restrict__ A,
                                                  const bf16* __restrict__ B,
                                                  OutT* __restrict__ C,
                                                  int lda, int ldb, int ldc,
                                                  int K, int gx)
{
    __shared__ __align__(16) bf16 As[2][16384];   // 2 x 32 KB
    __shared__ __align__(16) bf16 Bs[2][16384];   // 2 x 32 KB  (128 KB total)

    const int tid  = threadIdx.x;
    const int w    = tid >> 6;        // wave 0..7
    const int l    = tid & 63;
    const int quad = l >> 4;
    const int ln   = l & 15;
    const int wm   = w >> 2;          // 0..1
    const int wn   = w & 3;           // 0..3

    // T1: chunked XCD swizzle (gridDim.x % 8 == 0 -> bijective)
    const int nwg = gridDim.x;
    const int bid = blockIdx.x;
    const int swz = (bid & 7) * (nwg >> 3) + (bid >> 3);
    const int bx  = swz % gx;
    const int by  = swz / gx;
    const size_t mbase = (size_t)by * 256;
    const size_t nbase = (size_t)bx * 256;

    // staging map: thread t -> row t>>3 (of 64-row chunk), logical 8-elem
    // chunk (t&7)^(row&7)  [pre-swizzled source; linear LDS dest = m104-safe]
    const int srow   = tid >> 3;                  // 0..63
    const int schunk = (tid & 7) ^ (srow & 7);
    const bf16* Ag = A + (mbase + srow) * (size_t)lda + schunk * 8;
    const bf16* Bg = B + (nbase + srow) * (size_t)ldb + schunk * 8;

    // read-side element offsets (xor-swizzled k-chunk)
    const int xr = ln & 7;
    int aoff[8], bof[4], ksw[2];
#pragma unroll
    for (int i = 0; i < 8; ++i) aoff[i] = (wm * 128 + i * 16 + ln) * 64;
#pragma unroll
    for (int j = 0; j < 4; ++j) bof[j]  = (wn * 64  + j * 16 + ln) * 64;
#pragma unroll
    for (int kk = 0; kk < 2; ++kk) ksw[kk] = ((kk * 4 + quad) ^ xr) * 8;

    f32x4 acc[8][4];
#pragma unroll
    for (int i = 0; i < 8; ++i)
#pragma unroll
        for (int j = 0; j < 4; ++j) acc[i][j] = (f32x4){0.f, 0.f, 0.f, 0.f};

    bf16x8 Fa[2][8];   // A frags, double-banked by k-slot parity
    bf16x8 Fb[2][4];   // B frags, double-banked

    // prologue: stage tile0, drain+bar, issue k0(tile0) reads into bank0
    STAGE8(0, 0);
    asm volatile("s_waitcnt vmcnt(0)" ::: "memory");
    BAR();
    READS(0, 0, 0);                   // 12 in flight; drained by first lgkm(12)

    const int NT = K >> 6;            // 32 for K=2048 (even, >=4)
    int t = 0;
#pragma unroll 1
    for (; t < NT - 2; t += 2) {
        TILE(0, 1, t, 0);
        TILE(1, 0, t + 1, 0);
    }
    TILE(0, 1, NT - 2, 0);
    TILE(1, 0, NT - 1, 1);            // last tile: no stage, no next reads

    // C/D: col = ln, row = quad*4 + r  (m89/m91-verified)
#pragma unroll
    for (int i = 0; i < 8; ++i)
#pragma unroll
        for (int j = 0; j < 4; ++j)
#pragma unroll
            for (int r = 0; r < 4; ++r) {
                size_t row = mbase + wm * 128 + i * 16 + quad * 4 + r;
                size_t col = nbase + wn * 64 + j * 16 + ln;
                C[row * (size_t)ldc + col] = (OutT)acc[i][j][r];
            }
}

#undef BAR
#undef SB0
#undef READS
#undef MQ32
#undef STAGE8
#undef TILE

// ---------------------------------------------------------------------------
// Attention over fused buffer, RoPE fused in. One workgroup per (b,h).
// ---------------------------------------------------------------------------
__global__ __launch_bounds__(256) void attn_kernel(bf16* __restrict__ buf)
{
    __shared__ __align__(16) bf16 KP_lds[128 * 136];  // roped K, then P
    __shared__ __align__(16) bf16 Vt_lds[128 * 136];  // Vt[d][k] = V[k][d]

    const int bh = blockIdx.x;
    const int b  = bh >> 4;
    const int h  = bh & 15;
    const size_t baseQ = (size_t)b * SEQ * LDF + (size_t)h * D_HEAD;
    const size_t baseK = baseQ + KOFF;
    const size_t baseV = baseQ + VOFF;

    const int tid  = threadIdx.x;
    const int w    = tid >> 6;
    const int l    = tid & 63;
    const int quad = l >> 4;
    const int ln   = l & 15;

    // ---- stage roped K rows + V^T: thread -> row k=tid>>1, half d0=(tid&1)*64
    {
        int k  = tid >> 1;
        int d0 = (tid & 1) * 64;
        const bf16* kp = buf + baseK + (size_t)k * LDF + d0;
        const bf16* vp = buf + baseV + (size_t)k * LDF + d0;
        for (int c = 0; c < 8; ++c) {
            bf16x8 kv = *(const bf16x8*)(kp + c * 8);
            *(bf16x8*)&KP_lds[k * 136 + d0 + c * 8] = rope8(kv, k, d0 / 2 + c * 4);
            bf16x8 vv = *(const bf16x8*)(vp + c * 8);
            for (int j = 0; j < 8; ++j)
                Vt_lds[(d0 + c * 8 + j) * 136 + k] = vv[j];
        }
    }
    __syncthreads();

    const float rscale = 0.08838834764831845f;   // 1/sqrt(128)
    const float NEG    = -1e30f;

    // ---- phase 1: S = ropeQ @ ropeK^T for both strips, softmax in regs ----
    f32x4 acc2[2][8];
    for (int s = 0; s < 2; ++s)
        for (int nt = 0; nt < 8; ++nt) acc2[s][nt] = (f32x4){0.f, 0.f, 0.f, 0.f};

    for (int s = 0; s < 2; ++s) {
        const int q0 = w * 32 + s * 16;
        for (int kt = 0; kt < 4; ++kt) {
            bf16x8 qa = *(const bf16x8*)(buf + baseQ + (size_t)(q0 + ln) * LDF
                                           + kt * 32 + quad * 8);
            bf16x8 a = rope8(qa, q0 + ln, kt * 16 + quad * 4);
            for (int nt = 0; nt < 8; ++nt) {
                bf16x8 bb = *(const bf16x8*)&KP_lds[(nt * 16 + ln) * 136
                                                    + kt * 32 + quad * 8];
                acc2[s][nt] = mfma16(a, bb, acc2[s][nt]);
            }
        }

        float mx[4] = {NEG, NEG, NEG, NEG};
        for (int nt = 0; nt < 8; ++nt)
            for (int r = 0; r < 4; ++r) {
                int q = q0 + quad * 4 + r;
                int c = nt * 16 + ln;
                float v = acc2[s][nt][r] * rscale;
                v = (c <= q) ? v : NEG;
                acc2[s][nt][r] = v;
                mx[r] = fmaxf(mx[r], v);
            }
        for (int m = 1; m < 16; m <<= 1)
            for (int r = 0; r < 4; ++r)
                mx[r] = fmaxf(mx[r], __shfl_xor(mx[r], m));

        float sm[4] = {0.f, 0.f, 0.f, 0.f};
        for (int nt = 0; nt < 8; ++nt)
            for (int r = 0; r < 4; ++r) {
                float p = __expf(acc2[s][nt][r] - mx[r]);
                acc2[s][nt][r] = p;
                sm[r] += p;
            }
        for (int m = 1; m < 16; m <<= 1)
            for (int r = 0; r < 4; ++r)
                sm[r] += __shfl_xor(sm[r], m);

        for (int r = 0; r < 4; ++r) sm[r] = 1.0f / sm[r];
        for (int nt = 0; nt < 8; ++nt)
            for (int r = 0; r < 4; ++r)
                acc2[s][nt][r] *= sm[r];
    }

    __syncthreads();   // all K reads from KP_lds complete

    // ---- write P over the K region (own-wave rows only) ----
    for (int s = 0; s < 2; ++s)
        for (int nt = 0; nt < 8; ++nt)
            for (int r = 0; r < 4; ++r) {
                int q = w * 32 + s * 16 + quad * 4 + r;
                int c = nt * 16 + ln;
                KP_lds[q * 136 + c] = (bf16)acc2[s][nt][r];
            }

    // ---- phase 2: O = P @ V ----
    f32x4 o[2][8];
    for (int s = 0; s < 2; ++s)
        for (int nt = 0; nt < 8; ++nt) o[s][nt] = (f32x4){0.f, 0.f, 0.f, 0.f};

    for (int kt = 0; kt < 4; ++kt) {
        bf16x8 a0 = *(const bf16x8*)&KP_lds[(w * 32 +      ln) * 136 + kt * 32 + quad * 8];
        bf16x8 a1 = *(const bf16x8*)&KP_lds[(w * 32 + 16 + ln) * 136 + kt * 32 + quad * 8];
        for (int nt = 0; nt < 8; ++nt) {
            bf16x8 bb = *(const bf16x8*)&Vt_lds[(nt * 16 + ln) * 136 + kt * 32 + quad * 8];
            o[0][nt] = mfma16(a0, bb, o[0][nt]);
            o[1][nt] = mfma16(a1, bb, o[1][nt]);
        }
    }

    for (int s = 0; s < 2; ++s)
        for (int nt = 0; nt < 8; ++nt)
            for (int r = 0; r < 4; ++r) {
                int q = w * 32 + s * 16 + quad * 4 + r;
                int d = nt * 16 + ln;
                buf[baseQ + (size_t)q * LDF + d] = (bf16)o[s][nt][r];
            }
}

// ---------------------------------------------------------------------------
extern "C" void kernel_launch(void* const* d_in, const int* in_sizes, int n_in,
                              void* d_out, int out_size, void* d_ws, size_t ws_size,
                              hipStream_t stream)
{
    const float* x  = (const float*)d_in[0];
    const float* Wq = (const float*)d_in[1];
    const float* Wk = (const float*)d_in[2];
    const float* Wv = (const float*)d_in[3];
    const float* Wo = (const float*)d_in[4];
    float* out = (float*)d_out;

    // ws layout (bf16 elems): QKV 100.7 MB | xb 33.6 MB (WoB reuses) | WB 25.2 MB
    bf16* QKV = (bf16*)d_ws;
    bf16* xb  = QKV + (size_t)BT * LDF;
    bf16* WB  = xb + (size_t)BT * D_MODEL;
    bf16* WoB = xb;                               // free after QKV GEMM

    const int n8x = BT * D_MODEL / 8;             // 2,097,152
    const int n8w = D_MODEL * D_MODEL / 8;        //   524,288 = 2^19

    cvt_kernel<<<(n8x + 255) / 256, 256, 0, stream>>>(x, xb, n8x);
    cvt_w3<<<(3 * n8w) / 256, 256, 0, stream>>>(Wq, Wk, Wv, WB);

    // fused QKV projection: [8192 x 6144] = xb @ WB^T  (768 blocks, %8==0)
    gemm256<bf16><<<dim3((LDF / 256) * (BT / 256)), 512, 0, stream>>>(
        xb, WB, QKV, D_MODEL, D_MODEL, LDF, D_MODEL, LDF / 256);

    cvt_kernel<<<(n8w + 255) / 256, 256, 0, stream>>>(Wo, WoB, n8w);

    // attention with fused RoPE; O in-place over Q columns
    attn_kernel<<<BATCH * N_HEADS, 256, 0, stream>>>(QKV);

    // output projection: out[8192 x 2048] = O @ Wo^T (fp32 out, 256 blocks)
    gemm256<float><<<dim3((D_MODEL / 256) * (BT / 256)), 512, 0, stream>>>(
        QKV, WoB, out, LDF, D_MODEL, D_MODEL, D_MODEL, D_MODEL / 256);
}

// Round 7
// 539.957 us; speedup vs baseline: 1.0543x; 1.0543x over previous
//
#include <hip/hip_runtime.h>
#include <hip/hip_bf16.h>
#include <math.h>

#define D_MODEL 2048
#define N_HEADS 16
#define D_HEAD  128
#define BATCH   64
#define SEQ     128
#define BT      (BATCH*SEQ)   // 8192 rows
#define LDF     6144          // fused QKV row stride
#define KOFF    2048
#define VOFF    4096

typedef __bf16 bf16;
typedef __attribute__((ext_vector_type(8))) __bf16 bf16x8;
typedef __attribute__((ext_vector_type(4))) float  f32x4;

__device__ __forceinline__ f32x4 mfma16(bf16x8 a, bf16x8 b, f32x4 c) {
    return __builtin_amdgcn_mfma_f32_16x16x32_bf16(a, b, c, 0, 0, 0);
}

__device__ __forceinline__ bf16x8 cvt8_f32(const float* p) {
    f32x4 lo = *(const f32x4*)p;
    f32x4 hi = *(const f32x4*)(p + 4);
    bf16x8 r;
    r[0] = (bf16)lo[0]; r[1] = (bf16)lo[1]; r[2] = (bf16)lo[2]; r[3] = (bf16)lo[3];
    r[4] = (bf16)hi[0]; r[5] = (bf16)hi[1]; r[6] = (bf16)hi[2]; r[7] = (bf16)hi[3];
    return r;
}

// async global->LDS, 16 B/lane; LDS dest = wave-uniform base + lane*16 (m104)
__device__ __forceinline__ void gl2lds16(const bf16* g, bf16* l) {
    __builtin_amdgcn_global_load_lds(
        (const __attribute__((address_space(1))) void*)g,
        (__attribute__((address_space(3))) void*)l, 16, 0, 0);
}

// rope 8 consecutive d-elements (4 even/odd pairs)
__device__ __forceinline__ bf16x8 rope8(bf16x8 v, int tpos, int pair0) {
    bf16x8 r;
    for (int m = 0; m < 4; ++m) {
        int i = pair0 + m;
        float theta = __expf((float)(2 * i) * (-9.210340371976184f / 128.0f));
        float ang   = (float)tpos * theta;
        float sn, cs;
        __sincosf(ang, &sn, &cs);
        float e = (float)v[2 * m], o = (float)v[2 * m + 1];
        r[2 * m]     = (bf16)(e * cs - o * sn);
        r[2 * m + 1] = (bf16)(e * sn + o * cs);
    }
    return r;
}

// ---------------------------------------------------------------------------
__global__ __launch_bounds__(256) void cvt_kernel(const float* __restrict__ src,
                                                  bf16* __restrict__ dst, int n8)
{
    int i = blockIdx.x * 256 + threadIdx.x;
    if (i < n8) *(bf16x8*)(dst + (size_t)i * 8) = cvt8_f32(src + (size_t)i * 8);
}

__global__ __launch_bounds__(256) void cvt_w3(const float* __restrict__ w0,
                                              const float* __restrict__ w1,
                                              const float* __restrict__ w2,
                                              bf16* __restrict__ dst)
{
    int i   = blockIdx.x * 256 + threadIdx.x;     // < 3*2^19
    int sel = i >> 19;
    int off = i & ((1 << 19) - 1);
    const float* s = (sel == 0) ? w0 : (sel == 1) ? w1 : w2;
    *(bf16x8*)(dst + (size_t)i * 8) = cvt8_f32(s + (size_t)off * 8);
}

// ---------------------------------------------------------------------------
// gemm256: C[M,N] = A[M,K] @ B[N,K]^T, bf16 in, OutT out.
// 256x256 tile, BK=64, 512 thr = 8 waves (2Mx4N), per-wave 128x64 output.
//
// 4-phase cross-phase pipeline (register-budget-compliant: acc=128 AGPR,
// frags Fa[2][4]+Fb[2][4]=64 VGPR; launch_bounds(512,2) caps arch VGPR@128).
// Phase order (A-half, k-slot): P0=(0,k0) P1=(1,k0) P2=(1,k1) P3=(0,k1).
// Reads issued in phase p feed phase p+1's MFMA; counted lgkm waits drain
// exactly the FIFO head. ORDER-PINNING (r6 bugfix): every independent
// ds_read group boundary carries a sched_barrier(0) so the lgkm FIFO order
// is program order — P3's LGKM(4) then PROVABLY drains A01 (last reads of
// buffer BSEL) before STAGE8's DMA overwrites it (LDS WAR vs DMA is NOT
// protected by the compiler's register scoreboard). Prologue BAR also gets
// the SB0 fence (raw s_barrier is not a code-motion fence; without it the
// buffer-0 reads could hoist past the barrier into other waves' DMA window).
//   P0: issue A10->Fa1 |SB0| Bk1->Fb1; lgkm(8)->[Bk0,A00]; MFMA(0,Fa0,Fb0)
//   P1: issue A11->Fa0;               lgkm(8)->[A10];      MFMA(1,Fa1,Fb0)
//   P2: vmcnt(0)+BAR (t+1 staged 3 phases ago); issue A01->Fa1 |SB0|
//       Bk0(t+1)->Fb0; lgkm(8)->[Bk1,A11];                 MFMA(1,Fa0,Fb1)
//   P3: lgkm(4)->[A01]; BAR; STAGE8(t+2->own buf); A00(t+1)->Fa0;
//                                                          MFMA(0,Fa1,Fb1)
// 2 barriers/tile; B frags read ONCE per tile; 24 ds_read_b128/tile.
// ---------------------------------------------------------------------------

#define BAR() __builtin_amdgcn_s_barrier()
#define SB0() __builtin_amdgcn_sched_barrier(0)
#define LGKM(n) asm volatile("s_waitcnt lgkmcnt(" #n ")" ::: "memory")
#define VM0()   asm volatile("s_waitcnt vmcnt(0)"  ::: "memory")

// 4 A-frag ds_read_b128: half mh, k-slot ks -> FA[0..3]
#define READ_A4(BSEL, mh, ks, FA) do {                                        \
    _Pragma("unroll") for (int ii = 0; ii < 4; ++ii)                          \
        FA[ii] = *(const bf16x8*)&As[BSEL][aoff[(mh) * 4 + ii] + ksw[ks]];    \
    } while (0)

// 4 B-frag ds_read_b128: k-slot ks -> FB[0..3]
#define READ_B4(BSEL, ks, FB) do {                                            \
    _Pragma("unroll") for (int jj = 0; jj < 4; ++jj)                          \
        FB[jj] = *(const bf16x8*)&Bs[BSEL][bof[jj] + ksw[ks]];                \
    } while (0)

// 16 MFMA: acc half mh += FA x FB
#define MQ16(mh, FA, FB) do {                                                 \
    __builtin_amdgcn_s_setprio(1);                                            \
    _Pragma("unroll") for (int ii = 0; ii < 4; ++ii)                          \
    _Pragma("unroll") for (int jj = 0; jj < 4; ++jj)                          \
        acc[(mh) * 4 + ii][jj] = mfma16(FA[ii], FB[jj], acc[(mh) * 4 + ii][jj]); \
    __builtin_amdgcn_s_setprio(0);                                            \
    } while (0)

// stage full K-tile tt (A 4 chunks + B 4 chunks, 8KB each) into buffer BSEL
#define STAGE8(BSEL, tt) do {                                                 \
    const size_t _k = (size_t)(tt) * 64;                                      \
    _Pragma("unroll") for (int c = 0; c < 4; ++c) {                           \
        gl2lds16(Ag + (size_t)c * 64 * lda + _k, &As[BSEL][c*4096 + w*512]);  \
        gl2lds16(Bg + (size_t)c * 64 * ldb + _k, &Bs[BSEL][c*4096 + w*512]);  \
    } } while (0)

// MODE: 0 = steady; 1 = t==NT-2 (skip stage of t+2); 2 = t==NT-1 (tail)
#define TILE(BSEL, OSEL, tt, MODE) do {                                       \
    /* P0 */                                                                  \
    READ_A4(BSEL, 1, 0, Fa[1]); SB0(); READ_B4(BSEL, 1, Fb[1]);               \
    LGKM(8); SB0();                                                           \
    MQ16(0, Fa[0], Fb[0]);                                                    \
    SB0();                                                                    \
    /* P1 */                                                                  \
    READ_A4(BSEL, 1, 1, Fa[0]);                                               \
    LGKM(8); SB0();                                                           \
    MQ16(1, Fa[1], Fb[0]);                                                    \
    SB0();                                                                    \
    /* P2 */                                                                  \
    VM0(); BAR(); SB0();                                                      \
    READ_A4(BSEL, 0, 1, Fa[1]); SB0();                                        \
    if (MODE < 2) { READ_B4(OSEL, 0, Fb[0]); LGKM(8); } else { LGKM(4); }     \
    SB0();                                                                    \
    MQ16(1, Fa[0], Fb[1]);                                                    \
    SB0();                                                                    \
    /* P3 */                                                                  \
    if (MODE < 2) { LGKM(4); } else { LGKM(0); }                              \
    BAR(); SB0();                                                             \
    if (MODE == 0) STAGE8(BSEL, (tt) + 2);                                    \
    if (MODE < 2) READ_A4(OSEL, 0, 0, Fa[0]);                                 \
    SB0();                                                                    \
    MQ16(0, Fa[1], Fb[1]);                                                    \
    SB0();                                                                    \
    } while (0)

template<typename OutT>
__global__ __launch_bounds__(512, 2) void gemm256(const bf16* __restrict__ A,
                                                  const bf16* __restrict__ B,
                                                  OutT* __restrict__ C,
                                                  int lda, int ldb, int ldc,
                                                  int K, int gx)
{
    __shared__ __align__(16) bf16 As[2][16384];   // 2 x 32 KB
    __shared__ __align__(16) bf16 Bs[2][16384];   // 2 x 32 KB  (128 KB total)

    const int tid  = threadIdx.x;
    const int w    = tid >> 6;        // wave 0..7
    const int l    = tid & 63;
    const int quad = l >> 4;
    const int ln   = l & 15;
    const int wm   = w >> 2;          // 0..1
    const int wn   = w & 3;           // 0..3

    // T1: chunked XCD swizzle (gridDim.x % 8 == 0 -> bijective)
    const int nwg = gridDim.x;
    const int bid = blockIdx.x;
    const int swz = (bid & 7) * (nwg >> 3) + (bid >> 3);
    const int bx  = swz % gx;
    const int by  = swz / gx;
    const size_t mbase = (size_t)by * 256;
    const size_t nbase = (size_t)bx * 256;

    // staging map: thread t -> row t>>3 (of 64-row chunk), logical 8-elem
    // chunk (t&7)^(row&7)  [pre-swizzled source; linear LDS dest = m104-safe]
    const int srow   = tid >> 3;                  // 0..63
    const int schunk = (tid & 7) ^ (srow & 7);
    const bf16* Ag = A + (mbase + srow) * (size_t)lda + schunk * 8;
    const bf16* Bg = B + (nbase + srow) * (size_t)ldb + schunk * 8;

    // read-side element offsets (xor-swizzled k-chunk)
    const int xr = ln & 7;
    int aoff[8], bof[4], ksw[2];
#pragma unroll
    for (int i = 0; i < 8; ++i) aoff[i] = (wm * 128 + i * 16 + ln) * 64;
#pragma unroll
    for (int j = 0; j < 4; ++j) bof[j]  = (wn * 64  + j * 16 + ln) * 64;
#pragma unroll
    for (int kk = 0; kk < 2; ++kk) ksw[kk] = ((kk * 4 + quad) ^ xr) * 8;

    f32x4 acc[8][4];
#pragma unroll
    for (int i = 0; i < 8; ++i)
#pragma unroll
        for (int j = 0; j < 4; ++j) acc[i][j] = (f32x4){0.f, 0.f, 0.f, 0.f};

    bf16x8 Fa[2][4];   // A frags: bank alternates per phase
    bf16x8 Fb[2][4];   // B frags: [k-slot], resident whole tile

    // prologue = P2/P3 tail of virtual tile -1:
    // stage tile0, drain, bar (+SB0 fence: reads must NOT hoist into other
    // waves' DMA window); stage tile1; issue Bk0(t0)->Fb0 |SB0| A00(t0)->Fa0
    // => lgkm FIFO = [Bk0, A00] (8 outstanding)
    STAGE8(0, 0);
    VM0();
    BAR(); SB0();
    STAGE8(1, 1);
    READ_B4(0, 0, Fb[0]); SB0();
    READ_A4(0, 0, 0, Fa[0]); SB0();

    const int NT = K >> 6;            // 32 for K=2048 (even, >=4)
    int t = 0;
#pragma unroll 1
    for (; t < NT - 2; t += 2) {
        TILE(0, 1, t, 0);
        TILE(1, 0, t + 1, 0);
    }
    TILE(0, 1, NT - 2, 1);            // skip stage of tile NT
    TILE(1, 0, NT - 1, 2);            // tail: no next-tile reads/stage

    // C/D: col = ln, row = quad*4 + r  (m89/m91-verified)
#pragma unroll
    for (int i = 0; i < 8; ++i)
#pragma unroll
        for (int j = 0; j < 4; ++j)
#pragma unroll
            for (int r = 0; r < 4; ++r) {
                size_t row = mbase + wm * 128 + i * 16 + quad * 4 + r;
                size_t col = nbase + wn * 64 + j * 16 + ln;
                C[row * (size_t)ldc + col] = (OutT)acc[i][j][r];
            }
}

#undef BAR
#undef SB0
#undef LGKM
#undef VM0
#undef READ_A4
#undef READ_B4
#undef MQ16
#undef STAGE8
#undef TILE

// ---------------------------------------------------------------------------
// Attention over fused buffer, RoPE fused in. One workgroup per (b,h).
// ---------------------------------------------------------------------------
__global__ __launch_bounds__(256) void attn_kernel(bf16* __restrict__ buf)
{
    __shared__ __align__(16) bf16 KP_lds[128 * 136];  // roped K, then P
    __shared__ __align__(16) bf16 Vt_lds[128 * 136];  // Vt[d][k] = V[k][d]

    const int bh = blockIdx.x;
    const int b  = bh >> 4;
    const int h  = bh & 15;
    const size_t baseQ = (size_t)b * SEQ * LDF + (size_t)h * D_HEAD;
    const size_t baseK = baseQ + KOFF;
    const size_t baseV = baseQ + VOFF;

    const int tid  = threadIdx.x;
    const int w    = tid >> 6;
    const int l    = tid & 63;
    const int quad = l >> 4;
    const int ln   = l & 15;

    // ---- stage roped K rows + V^T: thread -> row k=tid>>1, half d0=(tid&1)*64
    {
        int k  = tid >> 1;
        int d0 = (tid & 1) * 64;
        const bf16* kp = buf + baseK + (size_t)k * LDF + d0;
        const bf16* vp = buf + baseV + (size_t)k * LDF + d0;
        for (int c = 0; c < 8; ++c) {
            bf16x8 kv = *(const bf16x8*)(kp + c * 8);
            *(bf16x8*)&KP_lds[k * 136 + d0 + c * 8] = rope8(kv, k, d0 / 2 + c * 4);
            bf16x8 vv = *(const bf16x8*)(vp + c * 8);
            for (int j = 0; j < 8; ++j)
                Vt_lds[(d0 + c * 8 + j) * 136 + k] = vv[j];
        }
    }
    __syncthreads();

    const float rscale = 0.08838834764831845f;   // 1/sqrt(128)
    const float NEG    = -1e30f;

    // ---- phase 1: S = ropeQ @ ropeK^T for both strips, softmax in regs ----
    f32x4 acc2[2][8];
    for (int s = 0; s < 2; ++s)
        for (int nt = 0; nt < 8; ++nt) acc2[s][nt] = (f32x4){0.f, 0.f, 0.f, 0.f};

    for (int s = 0; s < 2; ++s) {
        const int q0 = w * 32 + s * 16;
        for (int kt = 0; kt < 4; ++kt) {
            bf16x8 qa = *(const bf16x8*)(buf + baseQ + (size_t)(q0 + ln) * LDF
                                           + kt * 32 + quad * 8);
            bf16x8 a = rope8(qa, q0 + ln, kt * 16 + quad * 4);
            for (int nt = 0; nt < 8; ++nt) {
                bf16x8 bb = *(const bf16x8*)&KP_lds[(nt * 16 + ln) * 136
                                                    + kt * 32 + quad * 8];
                acc2[s][nt] = mfma16(a, bb, acc2[s][nt]);
            }
        }

        float mx[4] = {NEG, NEG, NEG, NEG};
        for (int nt = 0; nt < 8; ++nt)
            for (int r = 0; r < 4; ++r) {
                int q = q0 + quad * 4 + r;
                int c = nt * 16 + ln;
                float v = acc2[s][nt][r] * rscale;
                v = (c <= q) ? v : NEG;
                acc2[s][nt][r] = v;
                mx[r] = fmaxf(mx[r], v);
            }
        for (int m = 1; m < 16; m <<= 1)
            for (int r = 0; r < 4; ++r)
                mx[r] = fmaxf(mx[r], __shfl_xor(mx[r], m));

        float sm[4] = {0.f, 0.f, 0.f, 0.f};
        for (int nt = 0; nt < 8; ++nt)
            for (int r = 0; r < 4; ++r) {
                float p = __expf(acc2[s][nt][r] - mx[r]);
                acc2[s][nt][r] = p;
                sm[r] += p;
            }
        for (int m = 1; m < 16; m <<= 1)
            for (int r = 0; r < 4; ++r)
                sm[r] += __shfl_xor(sm[r], m);

        for (int r = 0; r < 4; ++r) sm[r] = 1.0f / sm[r];
        for (int nt = 0; nt < 8; ++nt)
            for (int r = 0; r < 4; ++r)
                acc2[s][nt][r] *= sm[r];
    }

    __syncthreads();   // all K reads from KP_lds complete

    // ---- write P over the K region (own-wave rows only) ----
    for (int s = 0; s < 2; ++s)
        for (int nt = 0; nt < 8; ++nt)
            for (int r = 0; r < 4; ++r) {
                int q = w * 32 + s * 16 + quad * 4 + r;
                int c = nt * 16 + ln;
                KP_lds[q * 136 + c] = (bf16)acc2[s][nt][r];
            }

    // ---- phase 2: O = P @ V ----
    f32x4 o[2][8];
    for (int s = 0; s < 2; ++s)
        for (int nt = 0; nt < 8; ++nt) o[s][nt] = (f32x4){0.f, 0.f, 0.f, 0.f};

    for (int kt = 0; kt < 4; ++kt) {
        bf16x8 a0 = *(const bf16x8*)&KP_lds[(w * 32 +      ln) * 136 + kt * 32 + quad * 8];
        bf16x8 a1 = *(const bf16x8*)&KP_lds[(w * 32 + 16 + ln) * 136 + kt * 32 + quad * 8];
        for (int nt = 0; nt < 8; ++nt) {
            bf16x8 bb = *(const bf16x8*)&Vt_lds[(nt * 16 + ln) * 136 + kt * 32 + quad * 8];
            o[0][nt] = mfma16(a0, bb, o[0][nt]);
            o[1][nt] = mfma16(a1, bb, o[1][nt]);
        }
    }

    for (int s = 0; s < 2; ++s)
        for (int nt = 0; nt < 8; ++nt)
            for (int r = 0; r < 4; ++r) {
                int q = w * 32 + s * 16 + quad * 4 + r;
                int d = nt * 16 + ln;
                buf[baseQ + (size_t)q * LDF + d] = (bf16)o[s][nt][r];
            }
}

// ---------------------------------------------------------------------------
extern "C" void kernel_launch(void* const* d_in, const int* in_sizes, int n_in,
                              void* d_out, int out_size, void* d_ws, size_t ws_size,
                              hipStream_t stream)
{
    const float* x  = (const float*)d_in[0];
    const float* Wq = (const float*)d_in[1];
    const float* Wk = (const float*)d_in[2];
    const float* Wv = (const float*)d_in[3];
    const float* Wo = (const float*)d_in[4];
    float* out = (float*)d_out;

    // ws layout (bf16 elems): QKV 100.7 MB | xb 33.6 MB (WoB reuses) | WB 25.2 MB
    bf16* QKV = (bf16*)d_ws;
    bf16* xb  = QKV + (size_t)BT * LDF;
    bf16* WB  = xb + (size_t)BT * D_MODEL;
    bf16* WoB = xb;                               // free after QKV GEMM

    const int n8x = BT * D_MODEL / 8;             // 2,097,152
    const int n8w = D_MODEL * D_MODEL / 8;        //   524,288 = 2^19

    cvt_kernel<<<(n8x + 255) / 256, 256, 0, stream>>>(x, xb, n8x);
    cvt_w3<<<(3 * n8w) / 256, 256, 0, stream>>>(Wq, Wk, Wv, WB);

    // fused QKV projection: [8192 x 6144] = xb @ WB^T  (768 blocks, %8==0)
    gemm256<bf16><<<dim3((LDF / 256) * (BT / 256)), 512, 0, stream>>>(
        xb, WB, QKV, D_MODEL, D_MODEL, LDF, D_MODEL, LDF / 256);

    cvt_kernel<<<(n8w + 255) / 256, 256, 0, stream>>>(Wo, WoB, n8w);

    // attention with fused RoPE; O in-place over Q columns
    attn_kernel<<<BATCH * N_HEADS, 256, 0, stream>>>(QKV);

    // output projection: out[8192 x 2048] = O @ Wo^T (fp32 out, 256 blocks)
    gemm256<float><<<dim3((D_MODEL / 256) * (BT / 256)), 512, 0, stream>>>(
        QKV, WoB, out, LDF, D_MODEL, D_MODEL, D_MODEL, D_MODEL / 256);
}

// Round 9
// 458.738 us; speedup vs baseline: 1.2409x; 1.1770x over previous
//
#include <hip/hip_runtime.h>
#include <hip/hip_bf16.h>
#include <math.h>

#define D_MODEL 2048
#define N_HEADS 16
#define D_HEAD  128
#define BATCH   64
#define SEQ     128
#define BT      (BATCH*SEQ)   // 8192 rows
#define LDF     6144          // fused QKV row stride
#define KOFF    2048
#define VOFF    4096

typedef __bf16 bf16;
typedef __attribute__((ext_vector_type(8))) __bf16 bf16x8;
typedef __attribute__((ext_vector_type(4))) float  f32x4;

__device__ __forceinline__ f32x4 mfma16(bf16x8 a, bf16x8 b, f32x4 c) {
    return __builtin_amdgcn_mfma_f32_16x16x32_bf16(a, b, c, 0, 0, 0);
}

__device__ __forceinline__ bf16x8 cvt8_f32(const float* p) {
    f32x4 lo = *(const f32x4*)p;
    f32x4 hi = *(const f32x4*)(p + 4);
    bf16x8 r;
    r[0] = (bf16)lo[0]; r[1] = (bf16)lo[1]; r[2] = (bf16)lo[2]; r[3] = (bf16)lo[3];
    r[4] = (bf16)hi[0]; r[5] = (bf16)hi[1]; r[6] = (bf16)hi[2]; r[7] = (bf16)hi[3];
    return r;
}

// async global->LDS, 16 B/lane; LDS dest = wave-uniform base + lane*16 (m104)
__device__ __forceinline__ void gl2lds16(const bf16* g, bf16* l) {
    __builtin_amdgcn_global_load_lds(
        (const __attribute__((address_space(1))) void*)g,
        (__attribute__((address_space(3))) void*)l, 16, 0, 0);
}

// rope 8 consecutive d-elements (4 even/odd pairs)
__device__ __forceinline__ bf16x8 rope8(bf16x8 v, int tpos, int pair0) {
    bf16x8 r;
    for (int m = 0; m < 4; ++m) {
        int i = pair0 + m;
        float theta = __expf((float)(2 * i) * (-9.210340371976184f / 128.0f));
        float ang   = (float)tpos * theta;
        float sn, cs;
        __sincosf(ang, &sn, &cs);
        float e = (float)v[2 * m], o = (float)v[2 * m + 1];
        r[2 * m]     = (bf16)(e * cs - o * sn);
        r[2 * m + 1] = (bf16)(e * sn + o * cs);
    }
    return r;
}

// ---------------------------------------------------------------------------
__global__ __launch_bounds__(256) void cvt_kernel(const float* __restrict__ src,
                                                  bf16* __restrict__ dst, int n8)
{
    int i = blockIdx.x * 256 + threadIdx.x;
    if (i < n8) *(bf16x8*)(dst + (size_t)i * 8) = cvt8_f32(src + (size_t)i * 8);
}

__global__ __launch_bounds__(256) void cvt_w3(const float* __restrict__ w0,
                                              const float* __restrict__ w1,
                                              const float* __restrict__ w2,
                                              bf16* __restrict__ dst)
{
    int i   = blockIdx.x * 256 + threadIdx.x;     // < 3*2^19
    int sel = i >> 19;
    int off = i & ((1 << 19) - 1);
    const float* s = (sel == 0) ? w0 : (sel == 1) ? w1 : w2;
    *(bf16x8*)(dst + (size_t)i * 8) = cvt8_f32(s + (size_t)off * 8);
}

// ---------------------------------------------------------------------------
// gemm256: C[M,N] = A[M,K] @ B[N,K]^T, bf16 in, OutT out.
// 256x256 tile, BK=64, 512 thr = 8 waves (2Mx4N), per-wave 128x64 output.
// 4 phases/K-tile, each: {ds_reads | 2x global_load_lds stage | SB0 |
// s_barrier | asm lgkmcnt(0) | SB0 | setprio(1) 16 MFMA setprio(0) |
// [P3: counted vmcnt] | SB0 | s_barrier}.
//
// OVERLAP MECHANISM (r7 post-mortem): the post-barrier lgkmcnt(0) creates a
// wave-stagger window — LDS services reads in issue order, so wave 0 exits
// its wait and starts MFMA while waves 6-7's reads are still in service;
// early waves' MFMA hides late waves' LDS time. r3's P0 pre-barrier LGKM(8)
// DEFEATED this on the heaviest phase (12 reads/wave): every wave waited
// ~2/3 of its LDS service BEFORE the barrier, so the barrier released at the
// end of the LDS window and all MFMA serialized after it. r8 change: that
// one line is removed. Everything else is r3-identical (best measured).
//
// Stage spread (2 calls/phase): tile t's P0..P2 stage tile t+1 chunks 2..7
// into the OTHER buffer (its reads finished at t-1's P2-end bar); P3 stages
// tile t+2 chunks 0,1 into OWN buffer (own reads drained by P2's lgkm0,
// barrier-ordered). vmcnt(2) once per tile at P3 end: drains tile t+1's 8
// chunks, keeps t+2's 2 newest in flight (never vmcnt(0) in steady state).
// ---------------------------------------------------------------------------

#define BAR() __builtin_amdgcn_s_barrier()
#define SB0() __builtin_amdgcn_sched_barrier(0)
#define WAIT_LGKM0() asm volatile("s_waitcnt lgkmcnt(0)" ::: "memory")

#define READ_A(BSEL, mh) do {                                                 \
    _Pragma("unroll") for (int ii = 0; ii < 4; ++ii)                          \
    _Pragma("unroll") for (int kk = 0; kk < 2; ++kk)                          \
        Af[ii][kk] = *(const bf16x8*)&As[BSEL][aoff[(mh)*4+ii] + ksw[kk]];    \
    } while (0)

#define READ_B(BSEL, j0) do {                                                 \
    _Pragma("unroll") for (int jj = 0; jj < 2; ++jj)                          \
    _Pragma("unroll") for (int kk = 0; kk < 2; ++kk)                          \
        Bf[(j0)+jj][kk] = *(const bf16x8*)&Bs[BSEL][bof[(j0)+jj] + ksw[kk]];  \
    } while (0)

#define MQ(i0, j0) do {                                                       \
    __builtin_amdgcn_s_setprio(1);                                            \
    _Pragma("unroll") for (int ii = 0; ii < 4; ++ii)                          \
    _Pragma("unroll") for (int jj = 0; jj < 2; ++jj)                          \
    _Pragma("unroll") for (int kk = 0; kk < 2; ++kk)                          \
        acc[(i0)+ii][(j0)+jj] =                                               \
            mfma16(Af[ii][kk], Bf[(j0)+jj][kk], acc[(i0)+ii][(j0)+jj]);       \
    __builtin_amdgcn_s_setprio(0);                                            \
    } while (0)

// stage one 64-row chunk (8 KB) of tile tt into buffer BSEL.
// c in 0..3 -> A rows c*64..; c in 4..7 -> B rows (c-4)*64..
#define STG1(BSEL, tt, c) do {                                                \
    if ((c) < 4)                                                              \
        gl2lds16(Ag + (size_t)(c) * 64 * lda + (size_t)(tt) * 64,             \
                 &As[BSEL][(c) * 4096 + w * 512]);                            \
    else                                                                      \
        gl2lds16(Bg + (size_t)((c) - 4) * 64 * ldb + (size_t)(tt) * 64,       \
                 &Bs[BSEL][((c) - 4) * 4096 + w * 512]);                      \
    } while (0)

// MODE: 0 = steady; 1 = pre-tail (stage t+1 only, vmcnt(0)); 2 = tail (none)
#define TILE_ITER(BSEL, OSEL, tt, MODE) do {                                  \
    /* ---- P0: A-half0 (8) + B01 (4) reads; stage t+1 c2,c3 ---- */          \
    READ_A(BSEL, 0); READ_B(BSEL, 0);                                         \
    if (MODE < 2) { STG1(OSEL, (tt) + 1, 2); STG1(OSEL, (tt) + 1, 3); }       \
    SB0(); BAR(); WAIT_LGKM0(); SB0();                                        \
    MQ(0, 0);                                                                 \
    SB0(); BAR();                                                             \
    /* ---- P1: B23 (4) reads; stage t+1 c4,c5 ---- */                        \
    READ_B(BSEL, 2);                                                          \
    if (MODE < 2) { STG1(OSEL, (tt) + 1, 4); STG1(OSEL, (tt) + 1, 5); }       \
    SB0(); BAR(); WAIT_LGKM0(); SB0();                                        \
    MQ(0, 2);                                                                 \
    SB0(); BAR();                                                             \
    /* ---- P2: A-half1 (8) reads; stage t+1 c6,c7 ---- */                    \
    READ_A(BSEL, 1);                                                          \
    if (MODE < 2) { STG1(OSEL, (tt) + 1, 6); STG1(OSEL, (tt) + 1, 7); }       \
    SB0(); BAR(); WAIT_LGKM0(); SB0();                                        \
    MQ(4, 2);                                                                 \
    SB0(); BAR();                                                             \
    /* ---- P3: no reads; stage t+2 c0,c1 into own buf; counted vmcnt ---- */ \
    if (MODE == 0) { STG1(BSEL, (tt) + 2, 0); STG1(BSEL, (tt) + 2, 1); }      \
    SB0(); BAR(); SB0();                                                      \
    MQ(4, 0);                                                                 \
    if (MODE == 0) asm volatile("s_waitcnt vmcnt(2)" ::: "memory");           \
    if (MODE == 1) asm volatile("s_waitcnt vmcnt(0)" ::: "memory");           \
    SB0(); BAR(); } while (0)

template<typename OutT>
__global__ __launch_bounds__(512, 2) void gemm256(const bf16* __restrict__ A,
                                                  const bf16* __restrict__ B,
                                                  OutT* __restrict__ C,
                                                  int lda, int ldb, int ldc,
                                                  int K, int gx)
{
    __shared__ __align__(16) bf16 As[2][16384];   // 2 x 32 KB
    __shared__ __align__(16) bf16 Bs[2][16384];   // 2 x 32 KB  (128 KB total)

    const int tid  = threadIdx.x;
    const int w    = tid >> 6;        // wave 0..7
    const int l    = tid & 63;
    const int quad = l >> 4;
    const int ln   = l & 15;
    const int wm   = w >> 2;          // 0..1
    const int wn   = w & 3;           // 0..3

    // T1: chunked XCD swizzle (gridDim.x % 8 == 0 -> bijective)
    const int nwg = gridDim.x;
    const int bid = blockIdx.x;
    const int swz = (bid & 7) * (nwg >> 3) + (bid >> 3);
    const int bx  = swz % gx;
    const int by  = swz / gx;
    const size_t mbase = (size_t)by * 256;
    const size_t nbase = (size_t)bx * 256;

    // staging map: thread t -> row t>>3 (of 64-row chunk), logical 8-elem
    // chunk (t&7)^(row&7)  [pre-swizzled source; linear LDS dest = m104-safe]
    const int srow   = tid >> 3;                  // 0..63
    const int schunk = (tid & 7) ^ (srow & 7);
    const bf16* Ag = A + (mbase + srow) * (size_t)lda + schunk * 8;
    const bf16* Bg = B + (nbase + srow) * (size_t)ldb + schunk * 8;

    // read-side element offsets (xor-swizzled k-chunk)
    const int xr = ln & 7;
    int aoff[8], bof[4], ksw[2];
#pragma unroll
    for (int i = 0; i < 8; ++i) aoff[i] = (wm * 128 + i * 16 + ln) * 64;
#pragma unroll
    for (int j = 0; j < 4; ++j) bof[j]  = (wn * 64  + j * 16 + ln) * 64;
#pragma unroll
    for (int kk = 0; kk < 2; ++kk) ksw[kk] = ((kk * 4 + quad) ^ xr) * 8;

    f32x4 acc[8][4];
#pragma unroll
    for (int i = 0; i < 8; ++i)
#pragma unroll
        for (int j = 0; j < 4; ++j) acc[i][j] = (f32x4){0.f, 0.f, 0.f, 0.f};

    bf16x8 Af[4][2];   // current A half
    bf16x8 Bf[4][2];   // all B frags for current K-tile

    // prologue: tile0 full burst + tile1 chunks 0,1  (10 calls in flight)
    STG1(0, 0, 0); STG1(0, 0, 1); STG1(0, 0, 2); STG1(0, 0, 3);
    STG1(0, 0, 4); STG1(0, 0, 5); STG1(0, 0, 6); STG1(0, 0, 7);
    STG1(1, 1, 0); STG1(1, 1, 1);
    asm volatile("s_waitcnt vmcnt(2)" ::: "memory");   // tile0 landed
    BAR();

    const int NT = K >> 6;            // 32 for K=2048 (even, >=4)
    int t = 0;
#pragma unroll 1
    for (; t < NT - 2; t += 2) {
        TILE_ITER(0, 1, t, 0);
        TILE_ITER(1, 0, t + 1, 0);
    }
    TILE_ITER(0, 1, NT - 2, 1);       // stages tile NT-1 tail chunks, vmcnt(0)
    TILE_ITER(1, 0, NT - 1, 2);       // last tile, nothing outstanding

    // C/D: col = ln, row = quad*4 + r  (m89/m91-verified)
#pragma unroll
    for (int i = 0; i < 8; ++i)
#pragma unroll
        for (int j = 0; j < 4; ++j)
#pragma unroll
            for (int r = 0; r < 4; ++r) {
                size_t row = mbase + wm * 128 + i * 16 + quad * 4 + r;
                size_t col = nbase + wn * 64 + j * 16 + ln;
                C[row * (size_t)ldc + col] = (OutT)acc[i][j][r];
            }
}

#undef BAR
#undef SB0
#undef WAIT_LGKM0
#undef READ_A
#undef READ_B
#undef MQ
#undef STG1
#undef TILE_ITER

// ---------------------------------------------------------------------------
// Attention over fused buffer, RoPE fused in. One workgroup per (b,h).
// ---------------------------------------------------------------------------
__global__ __launch_bounds__(256) void attn_kernel(bf16* __restrict__ buf)
{
    __shared__ __align__(16) bf16 KP_lds[128 * 136];  // roped K, then P
    __shared__ __align__(16) bf16 Vt_lds[128 * 136];  // Vt[d][k] = V[k][d]

    const int bh = blockIdx.x;
    const int b  = bh >> 4;
    const int h  = bh & 15;
    const size_t baseQ = (size_t)b * SEQ * LDF + (size_t)h * D_HEAD;
    const size_t baseK = baseQ + KOFF;
    const size_t baseV = baseQ + VOFF;

    const int tid  = threadIdx.x;
    const int w    = tid >> 6;
    const int l    = tid & 63;
    const int quad = l >> 4;
    const int ln   = l & 15;

    // ---- stage roped K rows + V^T: thread -> row k=tid>>1, half d0=(tid&1)*64
    {
        int k  = tid >> 1;
        int d0 = (tid & 1) * 64;
        const bf16* kp = buf + baseK + (size_t)k * LDF + d0;
        const bf16* vp = buf + baseV + (size_t)k * LDF + d0;
        for (int c = 0; c < 8; ++c) {
            bf16x8 kv = *(const bf16x8*)(kp + c * 8);
            *(bf16x8*)&KP_lds[k * 136 + d0 + c * 8] = rope8(kv, k, d0 / 2 + c * 4);
            bf16x8 vv = *(const bf16x8*)(vp + c * 8);
            for (int j = 0; j < 8; ++j)
                Vt_lds[(d0 + c * 8 + j) * 136 + k] = vv[j];
        }
    }
    __syncthreads();

    const float rscale = 0.08838834764831845f;   // 1/sqrt(128)
    const float NEG    = -1e30f;

    // ---- phase 1: S = ropeQ @ ropeK^T for both strips, softmax in regs ----
    f32x4 acc2[2][8];
    for (int s = 0; s < 2; ++s)
        for (int nt = 0; nt < 8; ++nt) acc2[s][nt] = (f32x4){0.f, 0.f, 0.f, 0.f};

    for (int s = 0; s < 2; ++s) {
        const int q0 = w * 32 + s * 16;
        for (int kt = 0; kt < 4; ++kt) {
            bf16x8 qa = *(const bf16x8*)(buf + baseQ + (size_t)(q0 + ln) * LDF
                                           + kt * 32 + quad * 8);
            bf16x8 a = rope8(qa, q0 + ln, kt * 16 + quad * 4);
            for (int nt = 0; nt < 8; ++nt) {
                bf16x8 bb = *(const bf16x8*)&KP_lds[(nt * 16 + ln) * 136
                                                    + kt * 32 + quad * 8];
                acc2[s][nt] = mfma16(a, bb, acc2[s][nt]);
            }
        }

        float mx[4] = {NEG, NEG, NEG, NEG};
        for (int nt = 0; nt < 8; ++nt)
            for (int r = 0; r < 4; ++r) {
                int q = q0 + quad * 4 + r;
                int c = nt * 16 + ln;
                float v = acc2[s][nt][r] * rscale;
                v = (c <= q) ? v : NEG;
                acc2[s][nt][r] = v;
                mx[r] = fmaxf(mx[r], v);
            }
        for (int m = 1; m < 16; m <<= 1)
            for (int r = 0; r < 4; ++r)
                mx[r] = fmaxf(mx[r], __shfl_xor(mx[r], m));

        float sm[4] = {0.f, 0.f, 0.f, 0.f};
        for (int nt = 0; nt < 8; ++nt)
            for (int r = 0; r < 4; ++r) {
                float p = __expf(acc2[s][nt][r] - mx[r]);
                acc2[s][nt][r] = p;
                sm[r] += p;
            }
        for (int m = 1; m < 16; m <<= 1)
            for (int r = 0; r < 4; ++r)
                sm[r] += __shfl_xor(sm[r], m);

        for (int r = 0; r < 4; ++r) sm[r] = 1.0f / sm[r];
        for (int nt = 0; nt < 8; ++nt)
            for (int r = 0; r < 4; ++r)
                acc2[s][nt][r] *= sm[r];
    }

    __syncthreads();   // all K reads from KP_lds complete

    // ---- write P over the K region (own-wave rows only) ----
    for (int s = 0; s < 2; ++s)
        for (int nt = 0; nt < 8; ++nt)
            for (int r = 0; r < 4; ++r) {
                int q = w * 32 + s * 16 + quad * 4 + r;
                int c = nt * 16 + ln;
                KP_lds[q * 136 + c] = (bf16)acc2[s][nt][r];
            }

    // ---- phase 2: O = P @ V ----
    f32x4 o[2][8];
    for (int s = 0; s < 2; ++s)
        for (int nt = 0; nt < 8; ++nt) o[s][nt] = (f32x4){0.f, 0.f, 0.f, 0.f};

    for (int kt = 0; kt < 4; ++kt) {
        bf16x8 a0 = *(const bf16x8*)&KP_lds[(w * 32 +      ln) * 136 + kt * 32 + quad * 8];
        bf16x8 a1 = *(const bf16x8*)&KP_lds[(w * 32 + 16 + ln) * 136 + kt * 32 + quad * 8];
        for (int nt = 0; nt < 8; ++nt) {
            bf16x8 bb = *(const bf16x8*)&Vt_lds[(nt * 16 + ln) * 136 + kt * 32 + quad * 8];
            o[0][nt] = mfma16(a0, bb, o[0][nt]);
            o[1][nt] = mfma16(a1, bb, o[1][nt]);
        }
    }

    for (int s = 0; s < 2; ++s)
        for (int nt = 0; nt < 8; ++nt)
            for (int r = 0; r < 4; ++r) {
                int q = w * 32 + s * 16 + quad * 4 + r;
                int d = nt * 16 + ln;
                buf[baseQ + (size_t)q * LDF + d] = (bf16)o[s][nt][r];
            }
}

// ---------------------------------------------------------------------------
extern "C" void kernel_launch(void* const* d_in, const int* in_sizes, int n_in,
                              void* d_out, int out_size, void* d_ws, size_t ws_size,
                              hipStream_t stream)
{
    const float* x  = (const float*)d_in[0];
    const float* Wq = (const float*)d_in[1];
    const float* Wk = (const float*)d_in[2];
    const float* Wv = (const float*)d_in[3];
    const float* Wo = (const float*)d_in[4];
    float* out = (float*)d_out;

    // ws layout (bf16 elems): QKV 100.7 MB | xb 33.6 MB (WoB reuses) | WB 25.2 MB
    bf16* QKV = (bf16*)d_ws;
    bf16* xb  = QKV + (size_t)BT * LDF;
    bf16* WB  = xb + (size_t)BT * D_MODEL;
    bf16* WoB = xb;                               // free after QKV GEMM

    const int n8x = BT * D_MODEL / 8;             // 2,097,152
    const int n8w = D_MODEL * D_MODEL / 8;        //   524,288 = 2^19

    cvt_kernel<<<(n8x + 255) / 256, 256, 0, stream>>>(x, xb, n8x);
    cvt_w3<<<(3 * n8w) / 256, 256, 0, stream>>>(Wq, Wk, Wv, WB);

    // fused QKV projection: [8192 x 6144] = xb @ WB^T  (768 blocks, %8==0)
    gemm256<bf16><<<dim3((LDF / 256) * (BT / 256)), 512, 0, stream>>>(
        xb, WB, QKV, D_MODEL, D_MODEL, LDF, D_MODEL, LDF / 256);

    cvt_kernel<<<(n8w + 255) / 256, 256, 0, stream>>>(Wo, WoB, n8w);

    // attention with fused RoPE; O in-place over Q columns
    attn_kernel<<<BATCH * N_HEADS, 256, 0, stream>>>(QKV);

    // output projection: out[8192 x 2048] = O @ Wo^T (fp32 out, 256 blocks)
    gemm256<float><<<dim3((D_MODEL / 256) * (BT / 256)), 512, 0, stream>>>(
        QKV, WoB, out, LDF, D_MODEL, D_MODEL, D_MODEL, D_MODEL / 256);
}